// Round 6
// baseline (42.786 us; speedup 1.0000x reference)
//
#include <hip/hip_runtime.h>
#include <hip/hip_fp16.h>

#define NHEADS 8
#define NPTS 4
#define EDIM 256
#define GRIDW 32
#define LTOK 1024  // 32*32
#define NTOK 4096  // 4 * 1024

// ---------------------------------------------------------------------------
// K0: convert query f32 -> f16 (halves gather L2 traffic).
// 1024 blocks x 256 threads, one float4 -> half4 per thread.
// ---------------------------------------------------------------------------
__global__ __launch_bounds__(256) void cvt_kernel(
    const float* __restrict__ q,     // [NTOK*EDIM]
    __half* __restrict__ qh)         // [NTOK*EDIM]
{
    const int i = blockIdx.x * 256 + threadIdx.x;   // float4 index
    const float4 v = *(const float4*)&q[i * 4];
    const __half2 h0 = __floats2half2_rn(v.x, v.y);
    const __half2 h1 = __floats2half2_rn(v.z, v.w);
    uint2 u;
    u.x = *(const unsigned int*)&h0;
    u.y = *(const unsigned int*)&h1;
    *(uint2*)&qh[i * 4] = u;
}

// ---------------------------------------------------------------------------
// Fully fused kernel: 512 blocks x 8 tokens x 512 threads (8 waves).
//  P1: stage 8 q-rows to LDS (f32)
//  P2a/P2b: offsets/attn GEMV, k-sliced (W delivered once/block)
//  P3: softmax + corner weights/indices
//  P4: bilinear gather from f16 query (8 B/lane taps, scalar-base loads)
//  P5: projection, k-split, 8 rows/thread (W_out delivered once/block)
//  P6: combine k-halves + bias, store
// ---------------------------------------------------------------------------
__global__ __launch_bounds__(512) void fused_all_kernel(
    const float* __restrict__ query,   // [NTOK,256] f32
    const __half* __restrict__ qh,     // [NTOK,256] f16
    const float* __restrict__ refp,    // [NTOK,2]
    const float* __restrict__ W_off,   // [256,64]
    const float* __restrict__ b_off,   // [64]
    const float* __restrict__ W_attn,  // [256,32]
    const float* __restrict__ b_attn,  // [32]
    const float* __restrict__ W_outp,  // [256,256]
    const float* __restrict__ b_out,   // [256]
    float* __restrict__ out)           // [NTOK,256]
{
    const int tb = blockIdx.x * 8;
    const int tid = threadIdx.x;

    __shared__ float qs[8][260];        // q rows; reused as gathered rows in P4+
    __shared__ float lg[8][96];         // logits
    __shared__ float cw[8][128];        // corner weights
    __shared__ int   ci[8][128];        // corner row base offsets (elements)
    __shared__ float ps[4096];          // 16KB partial-sum scratch

    // ---- P1: stage 8 q-rows ----
    {
        const int row = tid >> 6;
        const int c4 = (tid & 63) * 4;
        *(float4*)&qs[row][c4] = *(const float4*)&query[(tb + row) * EDIM + c4];
    }
    __syncthreads();

    // ---- P2a: offsets GEMV, k-sliced. wave = k-slice (32 k), lane = col ----
    {
        const int ks = tid >> 6;          // 0..7
        const int col = tid & 63;
        const int kbase = ks * 32;
        float a[8] = {};
        #pragma unroll 2
        for (int kk = 0; kk < 32; kk += 4) {
            const int k = kbase + kk;
            const float w0 = W_off[(k + 0) * 64 + col];
            const float w1 = W_off[(k + 1) * 64 + col];
            const float w2 = W_off[(k + 2) * 64 + col];
            const float w3 = W_off[(k + 3) * 64 + col];
            #pragma unroll
            for (int t = 0; t < 8; ++t) {
                const float4 q4 = *(const float4*)&qs[t][k];   // LDS broadcast
                a[t] = fmaf(q4.x, w0, a[t]);
                a[t] = fmaf(q4.y, w1, a[t]);
                a[t] = fmaf(q4.z, w2, a[t]);
                a[t] = fmaf(q4.w, w3, a[t]);
            }
        }
        #pragma unroll
        for (int t = 0; t < 8; ++t) ps[(ks * 8 + t) * 64 + col] = a[t];
    }
    __syncthreads();
    {   // reduce 8 k-slices -> lg[t][col]
        const int t = tid >> 6;
        const int col = tid & 63;
        float s = b_off[col];
        #pragma unroll
        for (int k = 0; k < 8; ++k) s += ps[(k * 8 + t) * 64 + col];
        lg[t][col] = s;
    }
    __syncthreads();

    // ---- P2b: attn GEMV, k-sliced. 16 slices x 16 k, lane = col (32) ----
    {
        const int ks = tid >> 5;          // 0..15
        const int col = tid & 31;
        const int kbase = ks * 16;
        float a[8] = {};
        #pragma unroll
        for (int kk = 0; kk < 16; kk += 4) {
            const int k = kbase + kk;
            const float w0 = W_attn[(k + 0) * 32 + col];
            const float w1 = W_attn[(k + 1) * 32 + col];
            const float w2 = W_attn[(k + 2) * 32 + col];
            const float w3 = W_attn[(k + 3) * 32 + col];
            #pragma unroll
            for (int t = 0; t < 8; ++t) {
                const float4 q4 = *(const float4*)&qs[t][k];
                a[t] = fmaf(q4.x, w0, a[t]);
                a[t] = fmaf(q4.y, w1, a[t]);
                a[t] = fmaf(q4.z, w2, a[t]);
                a[t] = fmaf(q4.w, w3, a[t]);
            }
        }
        #pragma unroll
        for (int t = 0; t < 8; ++t) ps[(ks * 8 + t) * 32 + col] = a[t];
    }
    __syncthreads();
    if (tid < 256) {   // reduce 16 k-slices -> lg[t][64+col]
        const int t = tid >> 5;
        const int col = tid & 31;
        float s = b_attn[col];
        #pragma unroll
        for (int k = 0; k < 16; ++k) s += ps[(k * 8 + t) * 32 + col];
        lg[t][64 + col] = s;
    }
    __syncthreads();

    // ---- P3: softmax + corners. threads 0..255 = 8 tok x 32 samples ----
    if (tid < 256) {
        const int t = tid >> 5;
        const int s = tid & 31;           // s = h*NPTS + p
        const int token = tb + t;
        const int n = token >> 10;
        const int h = s >> 2;
        const float l0 = lg[t][64 + h * 4 + 0];
        const float l1 = lg[t][64 + h * 4 + 1];
        const float l2 = lg[t][64 + h * 4 + 2];
        const float l3 = lg[t][64 + h * 4 + 3];
        const float m  = fmaxf(fmaxf(l0, l1), fmaxf(l2, l3));
        const float denom = __expf(l0 - m) + __expf(l1 - m) + __expf(l2 - m) + __expf(l3 - m);
        const float aw = __expf(lg[t][64 + s] - m) / (denom * (float)NHEADS);

        const float rx = refp[token * 2 + 0];
        const float ry = refp[token * 2 + 1];
        const float x = (rx + lg[t][2 * s + 0]) * 32.0f - 0.5f;
        const float y = (ry + lg[t][2 * s + 1]) * 32.0f - 0.5f;
        const float x0f = floorf(x);
        const float y0f = floorf(y);
        const float wx = x - x0f;
        const float wy = y - y0f;
        const int x0 = (int)x0f;
        const int y0 = (int)y0f;

        const int xi[4] = { x0, x0 + 1, x0, x0 + 1 };
        const int yi[4] = { y0, y0, y0 + 1, y0 + 1 };
        const float wc[4] = { (1.f - wx) * (1.f - wy), wx * (1.f - wy),
                              (1.f - wx) * wy,         wx * wy };
        #pragma unroll
        for (int c = 0; c < 4; ++c) {
            const bool valid = (xi[c] >= 0) & (xi[c] < GRIDW) & (yi[c] >= 0) & (yi[c] < GRIDW);
            cw[t][s * 4 + c] = valid ? (wc[c] * aw) : 0.f;
            ci[t][s * 4 + c] = valid ? ((n * LTOK + yi[c] * GRIDW + xi[c]) * EDIM) : 0;
        }
    }
    __syncthreads();

    // ---- P4: gather from f16 query. wave w -> token tb+w, 128 taps. ----
    {
        const int w = tid >> 6;
        const int lane = tid & 63;
        const int loff = lane * 4;        // in halves: 8 B per lane

        float4 acc = {0.f, 0.f, 0.f, 0.f};
        #pragma unroll 8
        for (int t = 0; t < 128; ++t) {
            const int sidx = __builtin_amdgcn_readfirstlane(ci[w][t]);
            const float wt = __uint_as_float(
                (unsigned)__builtin_amdgcn_readfirstlane((int)__float_as_uint(cw[w][t])));
            const uint2 u = *(const uint2*)&qh[sidx + loff];
            const float2 f0 = __half22float2(*(const __half2*)&u.x);
            const float2 f1 = __half22float2(*(const __half2*)&u.y);
            acc.x = fmaf(wt, f0.x, acc.x);
            acc.y = fmaf(wt, f0.y, acc.y);
            acc.z = fmaf(wt, f1.x, acc.z);
            acc.w = fmaf(wt, f1.y, acc.w);
        }
        *(float4*)&qs[w][loff] = acc;     // os[w]
    }
    __syncthreads();

    // ---- P5: projection. thread = (col pc, k-half kh); 8 rows per thread ----
    const int pc = tid & 255;
    const int kh = tid >> 8;              // 0 or 1
    float pacc[8] = {};
    {
        const int kbase = kh * 128;
        #pragma unroll 2
        for (int kk = 0; kk < 128; kk += 4) {
            const int k = kbase + kk;
            const float w0 = W_outp[(k + 0) * EDIM + pc];
            const float w1 = W_outp[(k + 1) * EDIM + pc];
            const float w2 = W_outp[(k + 2) * EDIM + pc];
            const float w3 = W_outp[(k + 3) * EDIM + pc];
            #pragma unroll
            for (int r = 0; r < 8; ++r) {
                const float4 a4 = *(const float4*)&qs[r][k];   // LDS broadcast
                pacc[r] = fmaf(a4.x, w0, pacc[r]);
                pacc[r] = fmaf(a4.y, w1, pacc[r]);
                pacc[r] = fmaf(a4.z, w2, pacc[r]);
                pacc[r] = fmaf(a4.w, w3, pacc[r]);
            }
        }
    }
    if (kh == 1) {
        #pragma unroll
        for (int r = 0; r < 8; ++r) ps[r * 256 + pc] = pacc[r];
    }
    __syncthreads();

    // ---- P6: combine + bias + store ----
    if (kh == 0) {
        const float bb = b_out[pc];
        #pragma unroll
        for (int r = 0; r < 8; ++r)
            out[(tb + r) * EDIM + pc] = pacc[r] + ps[r * 256 + pc] + bb;
    }
}

extern "C" void kernel_launch(void* const* d_in, const int* in_sizes, int n_in,
                              void* d_out, int out_size, void* d_ws, size_t ws_size,
                              hipStream_t stream) {
    const float* query  = (const float*)d_in[0];
    const float* refp   = (const float*)d_in[1];
    const float* W_off  = (const float*)d_in[2];
    const float* b_off  = (const float*)d_in[3];
    const float* W_attn = (const float*)d_in[4];
    const float* b_attn = (const float*)d_in[5];
    const float* W_out  = (const float*)d_in[6];
    const float* b_out  = (const float*)d_in[7];
    float* out = (float*)d_out;

    __half* qh = (__half*)d_ws;   // 2 MB f16 mirror of query

    cvt_kernel<<<NTOK * EDIM / 4 / 256, 256, 0, stream>>>(query, qh);
    fused_all_kernel<<<NTOK / 8, 512, 0, stream>>>(query, qh, refp, W_off, b_off,
                                                   W_attn, b_attn, W_out, b_out, out);
}

// Round 7
// 33.739 us; speedup vs baseline: 1.2681x; 1.2681x over previous
//
#include <hip/hip_runtime.h>

#define NHEADS 8
#define NPTS 4
#define EDIM 256
#define GRIDW 32
#define LTOK 1024  // 32*32
#define NTOK 4096  // 4 * 1024

// ---------------------------------------------------------------------------
// Fully fused kernel: 512 blocks x 8 tokens x 512 threads (8 waves).
//  P1: stage 8 q-rows to LDS
//  P2a/P2b: offsets/attn GEMV, k-sliced (W delivered once/block)
//  P3: softmax + corner weights/indices
//  P4: bilinear gather (f32, scalar-base row loads) -> LDS
//  P5: projection: thread = (col-group of 4, k-slice of 32); 8 rows/thread.
//      Each A b128 read feeds 16 FMAs (4x fewer LDS instrs than before).
//      8 k-slice partials combined via 2-barrier LDS tree in ps (32 KB).
// ---------------------------------------------------------------------------
__global__ __launch_bounds__(512) void fused_all_kernel(
    const float* __restrict__ query,   // [NTOK,256]
    const float* __restrict__ refp,    // [NTOK,2]
    const float* __restrict__ W_off,   // [256,64]
    const float* __restrict__ b_off,   // [64]
    const float* __restrict__ W_attn,  // [256,32]
    const float* __restrict__ b_attn,  // [32]
    const float* __restrict__ W_outp,  // [256,256]
    const float* __restrict__ b_out,   // [256]
    float* __restrict__ out)           // [NTOK,256]
{
    const int tb = blockIdx.x * 8;
    const int tid = threadIdx.x;

    __shared__ float qs[8][260];        // q rows; reused as gathered rows in P4+
    __shared__ float lg[8][96];         // logits
    __shared__ float cw[8][128];        // corner weights
    __shared__ int   ci[8][128];        // corner row base offsets (elements)
    __shared__ float ps[8192];          // 32KB scratch (GEMV partials / proj tree)

    // ---- P1: stage 8 q-rows ----
    {
        const int row = tid >> 6;
        const int c4 = (tid & 63) * 4;
        *(float4*)&qs[row][c4] = *(const float4*)&query[(tb + row) * EDIM + c4];
    }
    __syncthreads();

    // ---- P2a: offsets GEMV, k-sliced. wave = k-slice (32 k), lane = col ----
    {
        const int ks = tid >> 6;          // 0..7
        const int col = tid & 63;
        const int kbase = ks * 32;
        float a[8] = {};
        #pragma unroll 2
        for (int kk = 0; kk < 32; kk += 4) {
            const int k = kbase + kk;
            const float w0 = W_off[(k + 0) * 64 + col];
            const float w1 = W_off[(k + 1) * 64 + col];
            const float w2 = W_off[(k + 2) * 64 + col];
            const float w3 = W_off[(k + 3) * 64 + col];
            #pragma unroll
            for (int t = 0; t < 8; ++t) {
                const float4 q4 = *(const float4*)&qs[t][k];   // LDS broadcast
                a[t] = fmaf(q4.x, w0, a[t]);
                a[t] = fmaf(q4.y, w1, a[t]);
                a[t] = fmaf(q4.z, w2, a[t]);
                a[t] = fmaf(q4.w, w3, a[t]);
            }
        }
        #pragma unroll
        for (int t = 0; t < 8; ++t) ps[(ks * 8 + t) * 64 + col] = a[t];
    }
    __syncthreads();
    {   // reduce 8 k-slices -> lg[t][col]
        const int t = tid >> 6;
        const int col = tid & 63;
        float s = b_off[col];
        #pragma unroll
        for (int k = 0; k < 8; ++k) s += ps[(k * 8 + t) * 64 + col];
        lg[t][col] = s;
    }
    __syncthreads();

    // ---- P2b: attn GEMV, k-sliced. 16 slices x 16 k, lane = col (32) ----
    {
        const int ks = tid >> 5;          // 0..15
        const int col = tid & 31;
        const int kbase = ks * 16;
        float a[8] = {};
        #pragma unroll
        for (int kk = 0; kk < 16; kk += 4) {
            const int k = kbase + kk;
            const float w0 = W_attn[(k + 0) * 32 + col];
            const float w1 = W_attn[(k + 1) * 32 + col];
            const float w2 = W_attn[(k + 2) * 32 + col];
            const float w3 = W_attn[(k + 3) * 32 + col];
            #pragma unroll
            for (int t = 0; t < 8; ++t) {
                const float4 q4 = *(const float4*)&qs[t][k];
                a[t] = fmaf(q4.x, w0, a[t]);
                a[t] = fmaf(q4.y, w1, a[t]);
                a[t] = fmaf(q4.z, w2, a[t]);
                a[t] = fmaf(q4.w, w3, a[t]);
            }
        }
        #pragma unroll
        for (int t = 0; t < 8; ++t) ps[(ks * 8 + t) * 32 + col] = a[t];
    }
    __syncthreads();
    if (tid < 256) {   // reduce 16 k-slices -> lg[t][64+col]
        const int t = tid >> 5;
        const int col = tid & 31;
        float s = b_attn[col];
        #pragma unroll
        for (int k = 0; k < 16; ++k) s += ps[(k * 8 + t) * 32 + col];
        lg[t][64 + col] = s;
    }
    __syncthreads();

    // ---- P3: softmax + corners. threads 0..255 = 8 tok x 32 samples ----
    if (tid < 256) {
        const int t = tid >> 5;
        const int s = tid & 31;           // s = h*NPTS + p
        const int token = tb + t;
        const int n = token >> 10;
        const int h = s >> 2;
        const float l0 = lg[t][64 + h * 4 + 0];
        const float l1 = lg[t][64 + h * 4 + 1];
        const float l2 = lg[t][64 + h * 4 + 2];
        const float l3 = lg[t][64 + h * 4 + 3];
        const float m  = fmaxf(fmaxf(l0, l1), fmaxf(l2, l3));
        const float denom = __expf(l0 - m) + __expf(l1 - m) + __expf(l2 - m) + __expf(l3 - m);
        const float aw = __expf(lg[t][64 + s] - m) / (denom * (float)NHEADS);

        const float rx = refp[token * 2 + 0];
        const float ry = refp[token * 2 + 1];
        const float x = (rx + lg[t][2 * s + 0]) * 32.0f - 0.5f;
        const float y = (ry + lg[t][2 * s + 1]) * 32.0f - 0.5f;
        const float x0f = floorf(x);
        const float y0f = floorf(y);
        const float wx = x - x0f;
        const float wy = y - y0f;
        const int x0 = (int)x0f;
        const int y0 = (int)y0f;

        const int xi[4] = { x0, x0 + 1, x0, x0 + 1 };
        const int yi[4] = { y0, y0, y0 + 1, y0 + 1 };
        const float wc[4] = { (1.f - wx) * (1.f - wy), wx * (1.f - wy),
                              (1.f - wx) * wy,         wx * wy };
        #pragma unroll
        for (int c = 0; c < 4; ++c) {
            const bool valid = (xi[c] >= 0) & (xi[c] < GRIDW) & (yi[c] >= 0) & (yi[c] < GRIDW);
            cw[t][s * 4 + c] = valid ? (wc[c] * aw) : 0.f;
            ci[t][s * 4 + c] = valid ? ((n * LTOK + yi[c] * GRIDW + xi[c]) * EDIM) : 0;
        }
    }
    __syncthreads();

    // ---- P4: gather (f32). wave w -> token tb+w, 128 taps. Result -> qs. ----
    {
        const int w = tid >> 6;
        const int lane = tid & 63;
        const int loff = lane * 4;

        float4 acc = {0.f, 0.f, 0.f, 0.f};
        #pragma unroll 8
        for (int t = 0; t < 128; ++t) {
            const int sidx = __builtin_amdgcn_readfirstlane(ci[w][t]);
            const float wt = __uint_as_float(
                (unsigned)__builtin_amdgcn_readfirstlane((int)__float_as_uint(cw[w][t])));
            const float4 v = *(const float4*)&query[sidx + loff];
            acc.x = fmaf(wt, v.x, acc.x);
            acc.y = fmaf(wt, v.y, acc.y);
            acc.z = fmaf(wt, v.z, acc.z);
            acc.w = fmaf(wt, v.w, acc.w);
        }
        *(float4*)&qs[w][loff] = acc;     // gathered row w
    }
    __syncthreads();

    // ---- P5: projection. wave = k-slice ks (32 k), lane = col-group cg. ----
    // acc[r][c] for rows 0..7, cols 4cg..4cg+3, partial over ks's k range.
    {
        const int ks = tid >> 6;          // 0..7 (wave)
        const int cg = tid & 63;
        const int kbase = ks * 32;
        const int c0 = cg * 4;

        float4 acc[8];
        #pragma unroll
        for (int r = 0; r < 8; ++r) acc[r] = float4{0.f, 0.f, 0.f, 0.f};

        #pragma unroll 2
        for (int kk = 0; kk < 32; kk += 4) {
            const int k = kbase + kk;
            const float4 w0 = *(const float4*)&W_outp[(k + 0) * EDIM + c0];
            const float4 w1 = *(const float4*)&W_outp[(k + 1) * EDIM + c0];
            const float4 w2 = *(const float4*)&W_outp[(k + 2) * EDIM + c0];
            const float4 w3 = *(const float4*)&W_outp[(k + 3) * EDIM + c0];
            #pragma unroll
            for (int r = 0; r < 8; ++r) {
                const float4 a = *(const float4*)&qs[r][k];    // broadcast b128
                acc[r].x = fmaf(a.x, w0.x, acc[r].x);
                acc[r].y = fmaf(a.x, w0.y, acc[r].y);
                acc[r].z = fmaf(a.x, w0.z, acc[r].z);
                acc[r].w = fmaf(a.x, w0.w, acc[r].w);
                acc[r].x = fmaf(a.y, w1.x, acc[r].x);
                acc[r].y = fmaf(a.y, w1.y, acc[r].y);
                acc[r].z = fmaf(a.y, w1.z, acc[r].z);
                acc[r].w = fmaf(a.y, w1.w, acc[r].w);
                acc[r].x = fmaf(a.z, w2.x, acc[r].x);
                acc[r].y = fmaf(a.z, w2.y, acc[r].y);
                acc[r].z = fmaf(a.z, w2.z, acc[r].z);
                acc[r].w = fmaf(a.z, w2.w, acc[r].w);
                acc[r].x = fmaf(a.w, w3.x, acc[r].x);
                acc[r].y = fmaf(a.w, w3.y, acc[r].y);
                acc[r].z = fmaf(a.w, w3.z, acc[r].z);
                acc[r].w = fmaf(a.w, w3.w, acc[r].w);
            }
        }

        // ---- k-slice reduction tree: slices 4..7 -> ps, then 0..3 add ----
        if (ks >= 4) {
            float* dst = &ps[(ks - 4) * 2048];
            #pragma unroll
            for (int r = 0; r < 8; ++r)
                *(float4*)&dst[r * 256 + c0] = acc[r];
        }
        __syncthreads();
        if (ks < 4) {
            float* dst = &ps[ks * 2048];
            #pragma unroll
            for (int r = 0; r < 8; ++r) {
                float4 p = *(const float4*)&dst[r * 256 + c0];
                p.x += acc[r].x; p.y += acc[r].y;
                p.z += acc[r].z; p.w += acc[r].w;
                *(float4*)&dst[r * 256 + c0] = p;
            }
        }
        __syncthreads();
    }

    // ---- P6: final combine of 4 half-sums + bias, coalesced store ----
    {
        const int r = tid >> 6;
        const int c0 = (tid & 63) * 4;
        const float4 s0 = *(const float4*)&ps[0 * 2048 + r * 256 + c0];
        const float4 s1 = *(const float4*)&ps[1 * 2048 + r * 256 + c0];
        const float4 s2 = *(const float4*)&ps[2 * 2048 + r * 256 + c0];
        const float4 s3 = *(const float4*)&ps[3 * 2048 + r * 256 + c0];
        const float4 bb = *(const float4*)&b_out[c0];
        float4 o;
        o.x = ((s0.x + s1.x) + (s2.x + s3.x)) + bb.x;
        o.y = ((s0.y + s1.y) + (s2.y + s3.y)) + bb.y;
        o.z = ((s0.z + s1.z) + (s2.z + s3.z)) + bb.z;
        o.w = ((s0.w + s1.w) + (s2.w + s3.w)) + bb.w;
        *(float4*)&out[(tb + r) * EDIM + c0] = o;
    }
}

extern "C" void kernel_launch(void* const* d_in, const int* in_sizes, int n_in,
                              void* d_out, int out_size, void* d_ws, size_t ws_size,
                              hipStream_t stream) {
    const float* query  = (const float*)d_in[0];
    const float* refp   = (const float*)d_in[1];
    const float* W_off  = (const float*)d_in[2];
    const float* b_off  = (const float*)d_in[3];
    const float* W_attn = (const float*)d_in[4];
    const float* b_attn = (const float*)d_in[5];
    const float* W_out  = (const float*)d_in[6];
    const float* b_out  = (const float*)d_in[7];
    float* out = (float*)d_out;

    fused_all_kernel<<<NTOK / 8, 512, 0, stream>>>(query, refp, W_off, b_off,
                                                   W_attn, b_attn, W_out, b_out, out);
}